// Round 8
// baseline (72.452 us; speedup 1.0000x reference)
//
#include <hip/hip_runtime.h>

typedef float f2 __attribute__((ext_vector_type(2)));

static constexpr int B = 128;
static constexpr int G = 64;
static constexpr int P = 8732;
static constexpr float EPS = 1e-5f;
static constexpr float IOU_THR = 0.5f;

__device__ __forceinline__ void encode_store(
    float* out_loc, float* out_lab, int b, int p,
    float4 gb, float4 pr, int lab)
{
    float cx = (gb.x + gb.z) * 0.5f;
    float cy = (gb.y + gb.w) * 0.5f;
    float w  = gb.z - gb.x;
    float h  = gb.w - gb.y;
    float4 loc;
    loc.x = (cx - pr.x) / (pr.z * 0.1f);
    loc.y = (cy - pr.y) / (pr.w * 0.1f);
    loc.z = logf(w / pr.z) / 0.2f;
    loc.w = logf(h / pr.w) / 0.2f;
    *(float4*)(out_loc + (size_t)(b * P + p) * 4) = loc;
    out_lab[(size_t)b * P + p] = (float)lab;
}

// Fused single pass over all B*G*P IoUs, g processed in PAIRS via <2 x float>
// so the sub/mul/add/fma portion lowers to packed VOP3P (v_pk_*_f32).
// All per-element rounding is bit-identical to the scalar reference chain:
//   lt=max, rb=min, hw=max(rb-lt,0), ov=hw0*hw1, den=((ga+pa)-ov)+eps, ov/den
// with the division replaced by the correctly-rounded 6-op Markstein sequence
// (valid: den in [1e-5, 2.5], ov==0 or normal; x=0 -> +0 exactly).
// Contraction hazard blocked: t2 = fma(ov, -1, t1) == t1 - ov exactly (the
// product is exact), and intrinsic fma/fsub carry no 'contract' FMF.
__global__ __launch_bounds__(256, 8) void k_fused(
    const float* __restrict__ gt_boxes,       // [B,G,4] corner
    const int*   __restrict__ gt_labels,      // [B,G]
    const float* __restrict__ priors,         // [P,4] center
    unsigned long long* __restrict__ packed,  // [B,G]
    float* __restrict__ out_loc,              // [B,P,4]
    float* __restrict__ out_lab)              // [B,P]
{
    __shared__ float s_pk[5][G];               // field-major: x1,y1,x2,y2,area
    __shared__ unsigned long long s_red[G];
    __shared__ int   s_lab[G];
    __shared__ float s_iou[256][17];           // odd stride: 2-way alias = free

    const int b = blockIdx.y;
    const int t = threadIdx.x;
    const int pbase = blockIdx.x * 256;
    const int p = pbase + t;
    const bool valid = p < P;

    if (t < G) {
        float4 gb = *(const float4*)(gt_boxes + (size_t)(b * G + t) * 4);
        s_pk[0][t] = gb.x; s_pk[1][t] = gb.y;
        s_pk[2][t] = gb.z; s_pk[3][t] = gb.w;
        s_pk[4][t] = __fmul_rn(fmaxf(__fsub_rn(gb.z, gb.x), 0.0f),
                               fmaxf(__fsub_rn(gb.w, gb.y), 0.0f));
        s_lab[t] = gt_labels[b * G + t];
        s_red[t] = 0ull;
    }
    __syncthreads();

    // Invalid lanes: degenerate zero prior -> iou == +0.0f exactly for all g;
    // they occupy the largest row indices of the tail block, so ascending
    // strict-> scans and the ~p packing lose every tie to valid rows.
    float4 pr = make_float4(0.f, 0.f, 0.f, 0.f);
    if (valid) pr = *(const float4*)(priors + (size_t)p * 4);
    float hw = __fmul_rn(pr.z, 0.5f), hh = __fmul_rn(pr.w, 0.5f);
    float px1 = __fsub_rn(pr.x, hw), py1 = __fsub_rn(pr.y, hh);
    float px2 = __fadd_rn(pr.x, hw), py2 = __fadd_rn(pr.y, hh);
    float pa  = __fmul_rn(fmaxf(__fsub_rn(px2, px1), 0.0f),
                          fmaxf(__fsub_rn(py2, py1), 0.0f));

    // Hoisted splats (VOP3P takes no literals; these live once in VGPR pairs).
    const f2 vpx1 = {px1, px1}, vpy1 = {py1, py1};
    const f2 vpx2 = {px2, px2}, vpy2 = {py2, py2};
    const f2 vpa  = {pa, pa},   veps = {EPS, EPS};
    const f2 vone = {1.0f, 1.0f}, vnegone = {-1.0f, -1.0f};
    const f2 vzero = {0.0f, 0.0f};

    float bestIou = -1.0f;
    int   bestG   = 0;

    for (int q = 0; q < 4; ++q) {
        const int gbase = q * 16;
        // phase1: 16 ious as 8 packed pairs.
#pragma unroll
        for (int k2 = 0; k2 < 8; ++k2) {
            const int g0 = gbase + 2 * k2;
            // 8B-aligned broadcast pair loads (g0 even, 256B rows).
            f2 gx1 = *(const f2*)&s_pk[0][g0];
            f2 gy1 = *(const f2*)&s_pk[1][g0];
            f2 gx2 = *(const f2*)&s_pk[2][g0];
            f2 gy2 = *(const f2*)&s_pk[3][g0];
            f2 ga  = *(const f2*)&s_pk[4][g0];

            f2 ltx = __builtin_elementwise_max(gx1, vpx1);
            f2 lty = __builtin_elementwise_max(gy1, vpy1);
            f2 rbx = __builtin_elementwise_min(gx2, vpx2);
            f2 rby = __builtin_elementwise_min(gy2, vpy2);
            f2 dx  = rbx - ltx;                    // pk_add(neg) — exact sub
            f2 dy  = rby - lty;
            f2 ow  = __builtin_elementwise_max(dx, vzero);
            f2 oh  = __builtin_elementwise_max(dy, vzero);
            f2 ov  = ow * oh;                      // pk_mul
            f2 t1  = ga + vpa;                     // pk_add
            // t2 = t1 - ov, contraction-proof: fma(ov,-1,t1) is bit-identical.
            f2 t2  = __builtin_elementwise_fma(ov, vnegone, t1);
            f2 den = t2 + veps;                    // pk_add
            f2 r0  = {__builtin_amdgcn_rcpf(den.x), __builtin_amdgcn_rcpf(den.y)};
            f2 e   = __builtin_elementwise_fma(-den, r0, vone);
            f2 r1  = __builtin_elementwise_fma(e, r0, r0);
            f2 q0  = ov * r1;                      // pk_mul
            f2 rem = __builtin_elementwise_fma(-den, q0, ov);
            f2 qq  = __builtin_elementwise_fma(rem, r1, q0);

            s_iou[t][2 * k2]     = qq.x;           // merges to ds_write2_b32
            s_iou[t][2 * k2 + 1] = qq.y;
            if (qq.x > bestIou) { bestIou = qq.x; bestG = g0; }      // first-g
            if (qq.y > bestIou) { bestIou = qq.y; bestG = g0 + 1; }
        }
        __syncthreads();

        // phase2: per-g argmax over this block's 256 p's.
        // 16 threads per column (t&15 = col, t>>4 = row-group of 16); ascending
        // rows + strict > = smallest p wins ties; cross-thread/-block merge via
        // packed (iou<<32)|(~p) atomicMax (order-independent, deterministic).
        {
            const int c  = t & 15;
            const int r0s = (t >> 4) * 16;
            float bv = -0.5f;
            int   br = 0;
#pragma unroll
            for (int j = 0; j < 16; ++j) {
                float v = s_iou[r0s + j][c];
                if (v > bv) { bv = v; br = r0s + j; }
            }
            unsigned long long key =
                ((unsigned long long)__float_as_uint(bv) << 32) |
                (unsigned long long)(0xFFFFFFFFu - (unsigned)(pbase + br));
            atomicMax(&s_red[gbase + c], key);
        }
        __syncthreads();
    }

    if (t < G) {
        atomicMax(&packed[(size_t)b * G + t], s_red[t]);
    }

    if (valid) {
        float4 gb = make_float4(s_pk[0][bestG], s_pk[1][bestG],
                                s_pk[2][bestG], s_pk[3][bestG]);
        int lab = (bestIou < IOU_THR) ? 0 : s_lab[bestG];
        encode_store(out_loc, out_lab, b, p, gb, pr, lab);
    }
}

// Force-assign fixup: each gt overwrites its best prior; duplicate p resolved
// last-g-wins (matches jnp .at[].set scatter order).
__global__ __launch_bounds__(64) void k_fixup(
    const float* __restrict__ gt_boxes,
    const int*   __restrict__ gt_labels,
    const float* __restrict__ priors,
    const unsigned long long* __restrict__ packed,
    float* __restrict__ out_loc,
    float* __restrict__ out_lab)
{
    __shared__ int s_p[G];
    const int b = blockIdx.x;
    const int g = threadIdx.x;

    unsigned long long key = packed[(size_t)b * G + g];
    int p = (int)(0xFFFFFFFFu - (unsigned)(key & 0xFFFFFFFFull));
    s_p[g] = p;
    __syncthreads();

    bool win = true;
    for (int g2 = g + 1; g2 < G; ++g2)
        if (s_p[g2] == p) { win = false; break; }

    if (win) {
        float4 gb = *(const float4*)(gt_boxes + (size_t)(b * G + g) * 4);
        float4 pr = *(const float4*)(priors + (size_t)p * 4);
        int lab = gt_labels[b * G + g];   // forced: iou=2.0 >= thr, label kept
        encode_store(out_loc, out_lab, b, p, gb, pr, lab);
    }
}

extern "C" void kernel_launch(void* const* d_in, const int* in_sizes, int n_in,
                              void* d_out, int out_size, void* d_ws, size_t ws_size,
                              hipStream_t stream)
{
    const float* gt_boxes  = (const float*)d_in[0];
    const int*   gt_labels = (const int*)d_in[1];
    const float* priors    = (const float*)d_in[2];

    float* out_loc = (float*)d_out;                   // B*P*4 floats
    float* out_lab = out_loc + (size_t)B * P * 4;     // B*P floats
    unsigned long long* packed = (unsigned long long*)d_ws;  // B*G u64 (64 KB)

    // atomicMax is monotone: must zero each call (ws is 0xAA-poisoned once).
    hipMemsetAsync(packed, 0, (size_t)B * G * sizeof(unsigned long long), stream);

    k_fused<<<dim3((P + 255) / 256, B), 256, 0, stream>>>(
        gt_boxes, gt_labels, priors, packed, out_loc, out_lab);

    k_fixup<<<dim3(B), 64, 0, stream>>>(
        gt_boxes, gt_labels, priors, packed, out_loc, out_lab);
}